// Round 12
// baseline (769.375 us; speedup 1.0000x reference)
//
#include <hip/hip_runtime.h>
#include <stdint.h>

#define M_ROWS 8192
#define K_DIM  4096
#define N_DIM  11008
#define KSTEPS (K_DIM / 64)      // 64 K-tiles of BK=64

// ---- 256x256 geometry, 8 waves (2M x 4N), per-wave output 128x64 ----
#define BM 256
#define BN 256
#define MBLKS (M_ROWS / BM)      // 32
#define NBLKS (N_DIM / BN)       // 43
#define NWG   (MBLKS * NBLKS)    // 1376

typedef __attribute__((ext_vector_type(4)))  float          f32x4;
typedef __attribute__((ext_vector_type(16))) float          f32x16;
typedef __attribute__((ext_vector_type(8)))  __bf16         bf16x8;
typedef __attribute__((ext_vector_type(4)))  int            i32x4;
typedef __attribute__((ext_vector_type(8)))  unsigned short u16x8;

__constant__ float NF4_TBL[16] = {
    -1.0f, -0.6961928009986877f, -0.5250730514526367f, -0.39491748809814453f,
    -0.28444138169288635f, -0.18477343022823334f, -0.10644006729125977f,
    -0.029167551919817924f, 0.0f, 0.07958029955625534f, 0.16093020141124725f,
    0.24611230194568634f, 0.33791524171829224f, 0.44070982933044434f,
    0.5626170039176941f, 0.7229568362236023f};

__device__ __forceinline__ unsigned short f2bf(float f) {
  uint32_t u = __float_as_uint(f);
  u += 0x7fffu + ((u >> 16) & 1u);   // RNE
  return (unsigned short)(u >> 16);
}

__device__ __forceinline__ void gload_lds16(const void* g, const void* l) {
  __builtin_amdgcn_global_load_lds(
      (const __attribute__((address_space(1))) void*)(uintptr_t)g,
      (__attribute__((address_space(3))) void*)(uint32_t)(uintptr_t)l,
      16, 0, 0);
}

// ---------------- prep 1: x fp32 -> bf16 ----------------
__global__ void convert_x_kernel(const float* __restrict__ x,
                                 unsigned short* __restrict__ xb) {
  const long n8 = (long)M_ROWS * K_DIM / 8;
  for (long t = (long)blockIdx.x * blockDim.x + threadIdx.x; t < n8;
       t += (long)gridDim.x * blockDim.x) {
    const float* p = x + t * 8;
    f32x4 v0 = *(const f32x4*)p;
    f32x4 v1 = *(const f32x4*)(p + 4);
    u16x8 o;
    o[0] = f2bf(v0[0]); o[1] = f2bf(v0[1]); o[2] = f2bf(v0[2]); o[3] = f2bf(v0[3]);
    o[4] = f2bf(v1[0]); o[5] = f2bf(v1[1]); o[6] = f2bf(v1[2]); o[7] = f2bf(v1[3]);
    *(u16x8*)(xb + t * 8) = o;
  }
}

// ---------------- prep 2: NF4 dequant W -> bf16 ----------------
__global__ void dequant_w_kernel(const int* __restrict__ qw,
                                 const int* __restrict__ qs,
                                 const float* __restrict__ qf,
                                 const float* __restrict__ mean,
                                 unsigned short* __restrict__ wb) {
  __shared__ float tbl[16];
  if (threadIdx.x < 16) tbl[threadIdx.x] = NF4_TBL[threadIdx.x];
  __syncthreads();
  const float mu = mean[0];
  const long n8 = (long)N_DIM * K_DIM / 8;
  for (long t = (long)blockIdx.x * blockDim.x + threadIdx.x; t < n8;
       t += (long)gridDim.x * blockDim.x) {
    long f = t * 8;
    int  g = (int)(f >> 6);
    float s = (float)qs[g] / qf[g >> 8] + mu;
    i32x4 q0 = *(const i32x4*)(qw + f);
    i32x4 q1 = *(const i32x4*)(qw + f + 4);
    u16x8 o;
    o[0] = f2bf(tbl[q0[0]] * s); o[1] = f2bf(tbl[q0[1]] * s);
    o[2] = f2bf(tbl[q0[2]] * s); o[3] = f2bf(tbl[q0[3]] * s);
    o[4] = f2bf(tbl[q1[0]] * s); o[5] = f2bf(tbl[q1[1]] * s);
    o[6] = f2bf(tbl[q1[2]] * s); o[7] = f2bf(tbl[q1[3]] * s);
    *(u16x8*)(wb + f) = o;
  }
}

// ---------------- 256x256 bf16 GEMM, 32x32x16 MFMA:  C = A * B^T ----------------
// R11 kernel with CORRECTED swizzle involution (R11 had 6.76e7 bank conflicts:
// its granule XOR only used row&7, so 32-row fragment reads gave 4-way
// conflicts under stride-8 lane phasing). New per-row granule permutation:
//   rho(r) = (r&7) ^ (((r>>3)&3) << 1)          (self-inverse XOR)
// Staging (linear LDS dest): lane L of wave wid stages rows wid*8+(L>>3)
// (+64 for h1) -> (r>>3)&3 == wid&3 for both gloads -> source granule
//   scol/8 = (L&7) ^ (L>>3) ^ ((wid&3)<<1).
// Read: row = base32 + l31 (bases multiple of 32) -> granule
//   g_lds = (ks*2 + lid5) ^ (l31&7) ^ (((l31>>3)&3)<<1).
// Distinctness: consecutive-8 groups -> 8 distinct granules; stride-8 groups
// -> (rho>>1)&3 distinct across row-octets -> 8 distinct; consecutive-16 ->
// 2-way (free, = R8 level). Rest identical to R11/R8 skeleton: A triple
// buffer, B double buffer, 8 clusters w/ SB+setprio, 4 STG/tile, ONE
// vmcnt(4)+barrier boundary, R7 supertile map, anti-phase ring.
#define STG(GP, LB)                                                              \
  gload_lds16((GP) + (long)srow * K_DIM + scol, &LDSbuf[(LB) + wid * 1024]);     \
  gload_lds16((GP) + (long)(64 + srow) * K_DIM + scol,                           \
              &LDSbuf[(LB) + 8192 + wid * 1024]);

#define SB __builtin_amdgcn_sched_barrier(0)

#define KB(KS) (((((KS) * 2 + lid5) ^ l7 ^ rxtra) << 4))

// read A m-pair for m-half MH at k-slice KS from slot SA
#define RD_A32(DST, MH, KS, SA)                                                   \
  DST[0] = *(const bf16x8*)&LDSbuf[(SA) + aoffB + ((MH) * 2 + 0) * 4096 + KB(KS)];\
  DST[1] = *(const bf16x8*)&LDSbuf[(SA) + aoffB + ((MH) * 2 + 1) * 4096 + KB(KS)];

// read B n-pair at k-slice KS from buffer CB
#define RD_B32(DST, KS, CB)                                                       \
  DST[0] = *(const bf16x8*)&LDSbuf[(CB) + boffB + 0 * 4096 + KB(KS)];             \
  DST[1] = *(const bf16x8*)&LDSbuf[(CB) + boffB + 1 * 4096 + KB(KS)];

// one cluster: m-half MH x n0,n1 at current k-slice = 4 MFMA 32x32x16
#define CL32(MH, AF, BQ)                                                          \
  acc[(MH) * 2 + 0][0] = __builtin_amdgcn_mfma_f32_32x32x16_bf16(AF[0], BQ[0], acc[(MH) * 2 + 0][0], 0, 0, 0); \
  acc[(MH) * 2 + 1][0] = __builtin_amdgcn_mfma_f32_32x32x16_bf16(AF[1], BQ[0], acc[(MH) * 2 + 1][0], 0, 0, 0); \
  acc[(MH) * 2 + 0][1] = __builtin_amdgcn_mfma_f32_32x32x16_bf16(AF[0], BQ[1], acc[(MH) * 2 + 0][1], 0, 0, 0); \
  acc[(MH) * 2 + 1][1] = __builtin_amdgcn_mfma_f32_32x32x16_bf16(AF[1], BQ[1], acc[(MH) * 2 + 1][1], 0, 0, 0);

// full K-tile: k-slice ring rotated by BASE/2 (BASE=0 even waves, 4 odd)
#define TILE_BODY(BASE)                                                           \
    RD_A32(af_a, 0, (((BASE) >> 1) + 0) & 3, sAr);                                \
    RD_B32(bq_c, (((BASE) >> 1) + 0) & 3, cB);                                    \
    SB;                                                                           \
    RD_A32(af_b, 1, (((BASE) >> 1) + 0) & 3, sAr);                                \
    STG(wb + n0g * K_DIM + kB, nB);                                               \
    __builtin_amdgcn_s_setprio(1);                                                \
    CL32(0, af_a, bq_c)                                                           \
    __builtin_amdgcn_s_setprio(0);                                                \
    SB;                                                                           \
    RD_A32(af_a, 0, (((BASE) >> 1) + 1) & 3, sAr);                                \
    RD_B32(bq_n, (((BASE) >> 1) + 1) & 3, cB);                                    \
    STG(wb + (n0g + 128) * K_DIM + kB, nB + 16384);                               \
    __builtin_amdgcn_s_setprio(1);                                                \
    CL32(1, af_b, bq_c)                                                           \
    __builtin_amdgcn_s_setprio(0);                                                \
    SB;                                                                           \
    RD_A32(af_b, 1, (((BASE) >> 1) + 1) & 3, sAr);                                \
    STG(xb + m0g * K_DIM + kA, sAs);                                              \
    __builtin_amdgcn_s_setprio(1);                                                \
    CL32(0, af_a, bq_n)                                                           \
    __builtin_amdgcn_s_setprio(0);                                                \
    SB;                                                                           \
    RD_A32(af_a, 0, (((BASE) >> 1) + 2) & 3, sAr);                                \
    RD_B32(bq_c, (((BASE) >> 1) + 2) & 3, cB);                                    \
    STG(xb + (m0g + 128) * K_DIM + kA, sAs + 16384);                              \
    __builtin_amdgcn_s_setprio(1);                                                \
    CL32(1, af_b, bq_n)                                                           \
    __builtin_amdgcn_s_setprio(0);                                                \
    SB;                                                                           \
    RD_A32(af_b, 1, (((BASE) >> 1) + 2) & 3, sAr);                                \
    __builtin_amdgcn_s_setprio(1);                                                \
    CL32(0, af_a, bq_c)                                                           \
    __builtin_amdgcn_s_setprio(0);                                                \
    SB;                                                                           \
    RD_A32(af_a, 0, (((BASE) >> 1) + 3) & 3, sAr);                                \
    RD_B32(bq_n, (((BASE) >> 1) + 3) & 3, cB);                                    \
    __builtin_amdgcn_s_setprio(1);                                                \
    CL32(1, af_b, bq_c)                                                           \
    __builtin_amdgcn_s_setprio(0);                                                \
    SB;                                                                           \
    RD_A32(af_b, 1, (((BASE) >> 1) + 3) & 3, sAr);                                \
    __builtin_amdgcn_s_setprio(1);                                                \
    CL32(0, af_a, bq_n)                                                           \
    __builtin_amdgcn_s_setprio(0);                                                \
    SB;                                                                           \
    __builtin_amdgcn_s_setprio(1);                                                \
    CL32(1, af_b, bq_n)                                                           \
    __builtin_amdgcn_s_setprio(0);

#define TILE_SETUP                                                                \
    const int cur = t & 1;                                                        \
    const int cB = 98304 + cur * 32768;                                           \
    const int nB = 98304 + (cur ^ 1) * 32768;                                     \
    const long kB = (long)((t + 1 < KSTEPS ? t + 1 : KSTEPS - 1) * 64);           \
    const long kA = (long)((t + 2 < KSTEPS ? t + 2 : KSTEPS - 1) * 64);

#define TILE_BOUND                                                                \
    asm volatile("s_waitcnt vmcnt(4)");                                           \
    __builtin_amdgcn_sched_barrier(0);                                            \
    __builtin_amdgcn_s_barrier();                                                 \
    __builtin_amdgcn_sched_barrier(0);                                            \
    int tmp = sAr; sAr = sAn; sAn = sAs; sAs = tmp;

__global__ __launch_bounds__(512, 2) void gemm_pipe(
    const unsigned short* __restrict__ xb, const unsigned short* __restrict__ wb,
    float* __restrict__ C) {
  __align__(16) __shared__ unsigned char LDSbuf[163840];   // 96K A(3) + 64K B(2)

  const int tid = threadIdx.x;
  const int wid = tid >> 6, lane = tid & 63;
  const int wr = wid >> 2, wc = wid & 3;
  const int l31 = lane & 31, lid5 = lane >> 5, l7 = lane & 7;
  const int rxtra = ((l31 >> 3) & 3) << 1;   // rho(r) row-octet term on read side

  // ---- supertile mapping: 8mb x 4nb concurrent per XCD (R7-proven) ----
  const int p = ((int)blockIdx.x & 7) * (NWG / 8) + ((int)blockIdx.x >> 3);
  int mb, nb;
  if (p < 1280) {                 // 10 full nbg x 4 mbg x 32
    const int nbg = p >> 7;
    const int rem = p & 127;
    const int mbg = rem >> 5;
    const int s   = rem & 31;
    mb = mbg * 8 + (s & 7);
    nb = nbg * 4 + (s >> 3);
  } else {                        // ragged tail: nb 40..42, 4 mbg x 24
    const int q   = p - 1280;
    const int mbg = q / 24;
    const int s   = q % 24;
    mb = mbg * 8 + (s & 7);
    nb = 40 + (s >> 3);
  }
  const long m0g = (long)mb * BM, n0g = (long)nb * BN;

  // staging coords (per lane); corrected involution: source granule =
  // (L&7) ^ (L>>3) ^ ((wid&3)<<1)   [rho(r) with r = wid*8 + (L>>3) (+64)]
  const int srow = wid * 8 + (lane >> 3);
  const int scol = ((lane & 7) ^ (lane >> 3) ^ ((wid & 3) << 1)) * 8;

  // ds_read base coords (32x32 fragments)
  const int aoffB = (wr * 128 + l31) * 128;
  const int boffB = (wc * 64 + l31) * 128;

  // ---- prologue: A(0)->slot0, B(0)->par0, A(1)->slot1; wait all but A(1) ----
  STG(xb + m0g * K_DIM,              0);
  STG(xb + (m0g + 128) * K_DIM,      16384);
  STG(wb + n0g * K_DIM,              98304);
  STG(wb + (n0g + 128) * K_DIM,      98304 + 16384);
  STG(xb + m0g * K_DIM + 64,         32768);
  STG(xb + (m0g + 128) * K_DIM + 64, 32768 + 16384);
  asm volatile("s_waitcnt vmcnt(4)");
  __builtin_amdgcn_sched_barrier(0);
  __builtin_amdgcn_s_barrier();

  bf16x8 af_a[2], af_b[2], bq_c[2], bq_n[2];
  f32x16 acc[4][2] = {};

  int sAr = 0, sAn = 32768, sAs = 65536;   // A slots: read(t), read(t+1), stage(t+2)

  if ((wid & 1) == 0) {
    for (int t = 0; t < KSTEPS; ++t) {
      TILE_SETUP
      TILE_BODY(0)
      TILE_BOUND
    }
  } else {
    for (int t = 0; t < KSTEPS; ++t) {
      TILE_SETUP
      TILE_BODY(4)
      TILE_BOUND
    }
  }

  // ---- epilogue: 32x32 C/D layout col=lane&31, row=(reg&3)+8*(reg>>2)+4*lid5 ----
  const long crow = m0g + wr * 128;
  const long ccol = n0g + wc * 64 + l31;
#pragma unroll
  for (int mi = 0; mi < 4; ++mi)
#pragma unroll
    for (int ni = 0; ni < 2; ++ni)
#pragma unroll
      for (int reg = 0; reg < 16; ++reg) {
        const int row = (reg & 3) + 8 * (reg >> 2) + 4 * lid5;
        __builtin_nontemporal_store(
            acc[mi][ni][reg],
            &C[(crow + mi * 32 + row) * N_DIM + ccol + ni * 32]);
      }
}

// ---------------- fallback (no workspace): fused 128^2 kernel ----------------
__global__ __launch_bounds__(256) void gemm_fallback(
    const float* __restrict__ Xf, const int* __restrict__ qw,
    const int* __restrict__ qs, const float* __restrict__ qf,
    const float* __restrict__ meanp, float* __restrict__ C) {
  __shared__ unsigned short As[128 * 64];
  __shared__ unsigned short Bs[128 * 64];
  __shared__ float tbl[16];
  const int tid = threadIdx.x;
  if (tid < 16) tbl[tid] = NF4_TBL[tid];
  const float mu = meanp[0];
  const int nwg = (M_ROWS / 128) * (N_DIM / 128);
  const int wg = ((int)blockIdx.x & 7) * (nwg / 8) + ((int)blockIdx.x >> 3);
  const int mbf = wg % (M_ROWS / 128), nbf = wg / (M_ROWS / 128);
  const int m0 = mbf * 128, n0 = nbf * 128;
  const int wid = tid >> 6, lane = tid & 63;
  const int wrf = wid >> 1, wcc = wid & 1;
  const int r16 = lane & 15, hi = lane >> 4;
  f32x4 acc[4][4] = {};
  for (int t = 0; t < KSTEPS; ++t) {
    const int k0 = t * 64;
    __syncthreads();
#pragma unroll
    for (int i = 0; i < 4; ++i) {
      int gi = i * 256 + tid;
      int row = gi >> 3, kq = (gi & 7) * 8;
      const float* px = Xf + (long)(m0 + row) * K_DIM + k0 + kq;
      f32x4 v0 = *(const f32x4*)px;
      f32x4 v1 = *(const f32x4*)(px + 4);
      u16x8 o;
      o[0] = f2bf(v0[0]); o[1] = f2bf(v0[1]); o[2] = f2bf(v0[2]); o[3] = f2bf(v0[3]);
      o[4] = f2bf(v1[0]); o[5] = f2bf(v1[1]); o[6] = f2bf(v1[2]); o[7] = f2bf(v1[3]);
      *(u16x8*)&As[row * 64 + kq] = o;
    }
#pragma unroll
    for (int i = 0; i < 4; ++i) {
      int gi = i * 256 + tid;
      int row = gi >> 3, kq = (gi & 7) * 8;
      const int* pq = qw + (long)(n0 + row) * K_DIM + k0 + kq;
      i32x4 q0 = *(const i32x4*)pq;
      i32x4 q1 = *(const i32x4*)(pq + 4);
      int g = (n0 + row) * (K_DIM / 64) + t;
      float s = (float)qs[g] / qf[g >> 8] + mu;
      u16x8 o;
      o[0] = f2bf(tbl[q0[0]] * s); o[1] = f2bf(tbl[q0[1]] * s);
      o[2] = f2bf(tbl[q0[2]] * s); o[3] = f2bf(tbl[q0[3]] * s);
      o[4] = f2bf(tbl[q1[0]] * s); o[5] = f2bf(tbl[q1[1]] * s);
      o[6] = f2bf(tbl[q1[2]] * s); o[7] = f2bf(tbl[q1[3]] * s);
      *(u16x8*)&Bs[row * 64 + kq] = o;
    }
    __syncthreads();
    bf16x8 afr[4][2], bfr[4][2];
#pragma unroll
    for (int i = 0; i < 4; ++i)
#pragma unroll
      for (int h = 0; h < 2; ++h) {
        afr[i][h] = *(const bf16x8*)&As[(wrf * 64 + i * 16 + r16) * 64 + h * 32 + hi * 8];
        bfr[i][h] = *(const bf16x8*)&Bs[(wcc * 64 + i * 16 + r16) * 64 + h * 32 + hi * 8];
      }
#pragma unroll
    for (int i = 0; i < 4; ++i)
#pragma unroll
      for (int j = 0; j < 4; ++j) {
        acc[i][j] = __builtin_amdgcn_mfma_f32_16x16x32_bf16(afr[i][0], bfr[j][0], acc[i][j], 0, 0, 0);
        acc[i][j] = __builtin_amdgcn_mfma_f32_16x16x32_bf16(afr[i][1], bfr[j][1], acc[i][j], 0, 0, 0);
      }
  }
  const int crow = m0 + wrf * 64 + hi * 4;
  const int ccol = n0 + wcc * 64 + r16;
#pragma unroll
  for (int i = 0; i < 4; ++i)
#pragma unroll
    for (int j = 0; j < 4; ++j)
#pragma unroll
      for (int r = 0; r < 4; ++r)
        C[(long)(crow + i * 16 + r) * N_DIM + (ccol + j * 16)] = acc[i][j][r];
}

extern "C" void kernel_launch(void* const* d_in, const int* in_sizes, int n_in,
                              void* d_out, int out_size, void* d_ws, size_t ws_size,
                              hipStream_t stream) {
  const float* x    = (const float*)d_in[0];
  const int*   qw   = (const int*)d_in[1];
  const int*   qs   = (const int*)d_in[2];
  const float* qf   = (const float*)d_in[3];
  const float* mean = (const float*)d_in[4];
  float* out = (float*)d_out;

  const size_t xb_bytes = (size_t)M_ROWS * K_DIM * 2;  // 64 MiB
  const size_t wb_bytes = (size_t)N_DIM * K_DIM * 2;   // 86 MiB

  if (ws_size >= xb_bytes + wb_bytes) {
    unsigned short* xb = (unsigned short*)d_ws;
    unsigned short* wb = (unsigned short*)((char*)d_ws + xb_bytes);
    convert_x_kernel<<<4096, 256, 0, stream>>>(x, xb);
    dequant_w_kernel<<<4096, 256, 0, stream>>>(qw, qs, qf, mean, wb);
    gemm_pipe<<<NWG, 512, 0, stream>>>(xb, wb, out);
  } else {
    gemm_fallback<<<(M_ROWS / 128) * (N_DIM / 128), 256, 0, stream>>>(
        x, qw, qs, qf, mean, out);
  }
}

// Round 13
// 687.887 us; speedup vs baseline: 1.1185x; 1.1185x over previous
//
#include <hip/hip_runtime.h>
#include <stdint.h>

#define M_ROWS 8192
#define K_DIM  4096
#define N_DIM  11008
#define KSTEPS (K_DIM / 64)      // 64 K-tiles of BK=64

// ---- 256x256 geometry, 8 waves (2M x 4N), per-wave output 128x64 ----
#define BM 256
#define BN 256
#define MBLKS (M_ROWS / BM)      // 32
#define NBLKS (N_DIM / BN)       // 43
#define NWG   (MBLKS * NBLKS)    // 1376

typedef __attribute__((ext_vector_type(4))) float          f32x4;
typedef __attribute__((ext_vector_type(8))) __bf16         bf16x8;
typedef __attribute__((ext_vector_type(4))) int            i32x4;
typedef __attribute__((ext_vector_type(8))) unsigned short u16x8;

__constant__ float NF4_TBL[16] = {
    -1.0f, -0.6961928009986877f, -0.5250730514526367f, -0.39491748809814453f,
    -0.28444138169288635f, -0.18477343022823334f, -0.10644006729125977f,
    -0.029167551919817924f, 0.0f, 0.07958029955625534f, 0.16093020141124725f,
    0.24611230194568634f, 0.33791524171829224f, 0.44070982933044434f,
    0.5626170039176941f, 0.7229568362236023f};

__device__ __forceinline__ unsigned short f2bf(float f) {
  uint32_t u = __float_as_uint(f);
  u += 0x7fffu + ((u >> 16) & 1u);   // RNE
  return (unsigned short)(u >> 16);
}

__device__ __forceinline__ void gload_lds16(const void* g, const void* l) {
  __builtin_amdgcn_global_load_lds(
      (const __attribute__((address_space(1))) void*)(uintptr_t)g,
      (__attribute__((address_space(3))) void*)(uint32_t)(uintptr_t)l,
      16, 0, 0);
}

// ---------------- prep 1: x fp32 -> bf16 ----------------
__global__ void convert_x_kernel(const float* __restrict__ x,
                                 unsigned short* __restrict__ xb) {
  const long n8 = (long)M_ROWS * K_DIM / 8;
  for (long t = (long)blockIdx.x * blockDim.x + threadIdx.x; t < n8;
       t += (long)gridDim.x * blockDim.x) {
    const float* p = x + t * 8;
    f32x4 v0 = *(const f32x4*)p;
    f32x4 v1 = *(const f32x4*)(p + 4);
    u16x8 o;
    o[0] = f2bf(v0[0]); o[1] = f2bf(v0[1]); o[2] = f2bf(v0[2]); o[3] = f2bf(v0[3]);
    o[4] = f2bf(v1[0]); o[5] = f2bf(v1[1]); o[6] = f2bf(v1[2]); o[7] = f2bf(v1[3]);
    *(u16x8*)(xb + t * 8) = o;
  }
}

// ---------------- prep 2: NF4 dequant W -> bf16 ----------------
__global__ void dequant_w_kernel(const int* __restrict__ qw,
                                 const int* __restrict__ qs,
                                 const float* __restrict__ qf,
                                 const float* __restrict__ mean,
                                 unsigned short* __restrict__ wb) {
  __shared__ float tbl[16];
  if (threadIdx.x < 16) tbl[threadIdx.x] = NF4_TBL[threadIdx.x];
  __syncthreads();
  const float mu = mean[0];
  const long n8 = (long)N_DIM * K_DIM / 8;
  for (long t = (long)blockIdx.x * blockDim.x + threadIdx.x; t < n8;
       t += (long)gridDim.x * blockDim.x) {
    long f = t * 8;
    int  g = (int)(f >> 6);
    float s = (float)qs[g] / qf[g >> 8] + mu;
    i32x4 q0 = *(const i32x4*)(qw + f);
    i32x4 q1 = *(const i32x4*)(qw + f + 4);
    u16x8 o;
    o[0] = f2bf(tbl[q0[0]] * s); o[1] = f2bf(tbl[q0[1]] * s);
    o[2] = f2bf(tbl[q0[2]] * s); o[3] = f2bf(tbl[q0[3]] * s);
    o[4] = f2bf(tbl[q1[0]] * s); o[5] = f2bf(tbl[q1[1]] * s);
    o[6] = f2bf(tbl[q1[2]] * s); o[7] = f2bf(tbl[q1[3]] * s);
    *(u16x8*)(wb + f) = o;
  }
}

// ---------------- 256x256 one-barrier-per-tile bf16 GEMM:  C = A * B^T ----------------
// R8 skeleton EXACTLY (16x16x32 MFMA; A triple buffer slot t%3 at 0/32768/65536,
// B double buffer at 98304+par*32768; 8 clusters w/ per-cluster SB+setprio; 4
// STG/tile (B(t+1)h0,h1 then A(t+2)h0,h1); ONE vmcnt(4)+barrier boundary; T2
// swizzle; R7 supertile map; anti-phase ring +4 for odd waves).
// NEW: cross-tile A pre-read. af_a is dead after c5; A(t+1)'s slot sAn has been
// resident since tile-t start (staged t-1, vmcnt'd+barrier'd; nothing writes
// sAn during t). c6 pre-reads next tile's first A m-pair from sAn into af_a ->
// fills c6/c7's idle LDS pipe (wind-down) and removes 4 A-reads from the
// post-barrier critical path (wind-up): c0's first MFMA now waits on 4 B reads
// only. Prologue preloads af_a for t=0. Ledger unchanged.
#define STG(GP, LB)                                                              \
  gload_lds16((GP) + (long)srow * K_DIM + scol, &LDSbuf[(LB) + wid * 1024]);     \
  gload_lds16((GP) + (long)(64 + srow) * K_DIM + scol,                           \
              &LDSbuf[(LB) + 8192 + wid * 1024]);

#define SB __builtin_amdgcn_sched_barrier(0)

#define RD_A2(DST, MB, SA)                                                        \
  DST[0][0] = *(const bf16x8*)&LDSbuf[(SA) + aoff + (MB) * 2048 + kswz0];         \
  DST[0][1] = *(const bf16x8*)&LDSbuf[(SA) + aoff + (MB) * 2048 + kswz1];         \
  DST[1][0] = *(const bf16x8*)&LDSbuf[(SA) + aoff + ((MB) + 1) * 2048 + kswz0];   \
  DST[1][1] = *(const bf16x8*)&LDSbuf[(SA) + aoff + ((MB) + 1) * 2048 + kswz1];

#define RD_B2(NB, CB)                                                             \
  bq[NB][0]     = *(const bf16x8*)&LDSbuf[(CB) + boff + (NB) * 2048 + kswz0];     \
  bq[NB][1]     = *(const bf16x8*)&LDSbuf[(CB) + boff + (NB) * 2048 + kswz1];     \
  bq[NB + 1][0] = *(const bf16x8*)&LDSbuf[(CB) + boff + ((NB) + 1) * 2048 + kswz0];\
  bq[NB + 1][1] = *(const bf16x8*)&LDSbuf[(CB) + boff + ((NB) + 1) * 2048 + kswz1];

#define MFP(MI, AF, AI, NI)                                                       \
  acc[MI][NI] = __builtin_amdgcn_mfma_f32_16x16x32_bf16(AF[AI][0], bq[NI][0], acc[MI][NI], 0, 0, 0); \
  acc[MI][NI] = __builtin_amdgcn_mfma_f32_16x16x32_bf16(AF[AI][1], bq[NI][1], acc[MI][NI], 0, 0, 0);

// full K-tile body, cluster ring rotated by BASE (0 even waves, 4 odd).
// af_a enters holding this tile's (BASE+0,+1) m-pair (preloaded by previous
// tile's c6 or the prologue). c6 pre-reads NEXT tile's (BASE+0,+1) from sAn.
#define TILE_BODY(BASE)                                                           \
    RD_B2(0, cB);                                                                 \
    SB;                                                                           \
    RD_B2(2, cB);                                                                 \
    STG(wb + n0g * K_DIM + kB, nB);                                               \
    __builtin_amdgcn_s_setprio(1);                                                \
    MFP(((BASE) + 0) & 7, af_a, 0, 0) MFP(((BASE) + 1) & 7, af_a, 1, 0)           \
    MFP(((BASE) + 0) & 7, af_a, 0, 1) MFP(((BASE) + 1) & 7, af_a, 1, 1)           \
    __builtin_amdgcn_s_setprio(0);                                                \
    SB;                                                                           \
    RD_A2(af_b, ((BASE) + 2) & 7, sAr);                                           \
    STG(wb + (n0g + 128) * K_DIM + kB, nB + 16384);                               \
    __builtin_amdgcn_s_setprio(1);                                                \
    MFP(((BASE) + 0) & 7, af_a, 0, 2) MFP(((BASE) + 1) & 7, af_a, 1, 2)           \
    MFP(((BASE) + 0) & 7, af_a, 0, 3) MFP(((BASE) + 1) & 7, af_a, 1, 3)           \
    __builtin_amdgcn_s_setprio(0);                                                \
    SB;                                                                           \
    STG(xb + m0g * K_DIM + kA, sAs);                                              \
    __builtin_amdgcn_s_setprio(1);                                                \
    MFP(((BASE) + 2) & 7, af_b, 0, 2) MFP(((BASE) + 3) & 7, af_b, 1, 2)           \
    MFP(((BASE) + 2) & 7, af_b, 0, 3) MFP(((BASE) + 3) & 7, af_b, 1, 3)           \
    __builtin_amdgcn_s_setprio(0);                                                \
    SB;                                                                           \
    RD_A2(af_a, ((BASE) + 4) & 7, sAr);                                           \
    STG(xb + (m0g + 128) * K_DIM + kA, sAs + 16384);                              \
    __builtin_amdgcn_s_setprio(1);                                                \
    MFP(((BASE) + 2) & 7, af_b, 0, 0) MFP(((BASE) + 3) & 7, af_b, 1, 0)           \
    MFP(((BASE) + 2) & 7, af_b, 0, 1) MFP(((BASE) + 3) & 7, af_b, 1, 1)           \
    __builtin_amdgcn_s_setprio(0);                                                \
    SB;                                                                           \
    __builtin_amdgcn_s_setprio(1);                                                \
    MFP(((BASE) + 4) & 7, af_a, 0, 0) MFP(((BASE) + 5) & 7, af_a, 1, 0)           \
    MFP(((BASE) + 4) & 7, af_a, 0, 1) MFP(((BASE) + 5) & 7, af_a, 1, 1)           \
    __builtin_amdgcn_s_setprio(0);                                                \
    SB;                                                                           \
    RD_A2(af_b, ((BASE) + 6) & 7, sAr);                                           \
    __builtin_amdgcn_s_setprio(1);                                                \
    MFP(((BASE) + 4) & 7, af_a, 0, 2) MFP(((BASE) + 5) & 7, af_a, 1, 2)           \
    MFP(((BASE) + 4) & 7, af_a, 0, 3) MFP(((BASE) + 5) & 7, af_a, 1, 3)           \
    __builtin_amdgcn_s_setprio(0);                                                \
    SB;                                                                           \
    RD_A2(af_a, ((BASE) + 0) & 7, sAn);   /* cross-tile pre-read for t+1 */       \
    __builtin_amdgcn_s_setprio(1);                                                \
    MFP(((BASE) + 6) & 7, af_b, 0, 2) MFP(((BASE) + 7) & 7, af_b, 1, 2)           \
    MFP(((BASE) + 6) & 7, af_b, 0, 3) MFP(((BASE) + 7) & 7, af_b, 1, 3)           \
    __builtin_amdgcn_s_setprio(0);                                                \
    SB;                                                                           \
    __builtin_amdgcn_s_setprio(1);                                                \
    MFP(((BASE) + 6) & 7, af_b, 0, 0) MFP(((BASE) + 7) & 7, af_b, 1, 0)           \
    MFP(((BASE) + 6) & 7, af_b, 0, 1) MFP(((BASE) + 7) & 7, af_b, 1, 1)           \
    __builtin_amdgcn_s_setprio(0);

#define TILE_SETUP                                                                \
    const int cur = t & 1;                                                        \
    const int cB = 98304 + cur * 32768;                                           \
    const int nB = 98304 + (cur ^ 1) * 32768;                                     \
    const long kB = (long)((t + 1 < KSTEPS ? t + 1 : KSTEPS - 1) * 64);           \
    const long kA = (long)((t + 2 < KSTEPS ? t + 2 : KSTEPS - 1) * 64);

#define TILE_BOUND                                                                \
    asm volatile("s_waitcnt vmcnt(4)");                                           \
    __builtin_amdgcn_sched_barrier(0);                                            \
    __builtin_amdgcn_s_barrier();                                                 \
    __builtin_amdgcn_sched_barrier(0);                                            \
    int tmp = sAr; sAr = sAn; sAn = sAs; sAs = tmp;

__global__ __launch_bounds__(512, 2) void gemm_pipe(
    const unsigned short* __restrict__ xb, const unsigned short* __restrict__ wb,
    float* __restrict__ C) {
  __align__(16) __shared__ unsigned char LDSbuf[163840];   // 96K A(3) + 64K B(2)

  const int tid = threadIdx.x;
  const int wid = tid >> 6, lane = tid & 63;
  const int wr = wid >> 2, wc = wid & 3;
  const int r16 = lane & 15, hi = lane >> 4;

  // ---- supertile mapping: 8mb x 4nb concurrent per XCD (R7-proven) ----
  const int p = ((int)blockIdx.x & 7) * (NWG / 8) + ((int)blockIdx.x >> 3);
  int mb, nb;
  if (p < 1280) {                 // 10 full nbg x 4 mbg x 32
    const int nbg = p >> 7;
    const int rem = p & 127;
    const int mbg = rem >> 5;
    const int s   = rem & 31;
    mb = mbg * 8 + (s & 7);
    nb = nbg * 4 + (s >> 3);
  } else {                        // ragged tail: nb 40..42, 4 mbg x 24
    const int q   = p - 1280;
    const int mbg = q / 24;
    const int s   = q % 24;
    mb = mbg * 8 + (s & 7);
    nb = 40 + (s >> 3);
  }
  const long m0g = (long)mb * BM, n0g = (long)nb * BN;

  // staging coords (per lane); T2: linear LDS dest, inverse-swizzled source
  const int srow = wid * 8 + (lane >> 3);
  const int scol = ((lane & 7) ^ (lane >> 3)) * 8;

  // ds_read coords (T2 swizzle on read)
  const int aoff = (wr * 128 + r16) * 128;
  const int boff = (wc * 64 + r16) * 128;
  const int kswz0 = ((hi ^ (r16 & 7)) << 4);
  const int kswz1 = kswz0 ^ 64;

  // ---- prologue: A(0)->slot0, B(0)->par0, A(1)->slot1; wait all but A(1) ----
  STG(xb + m0g * K_DIM,              0);
  STG(xb + (m0g + 128) * K_DIM,      16384);
  STG(wb + n0g * K_DIM,              98304);
  STG(wb + (n0g + 128) * K_DIM,      98304 + 16384);
  STG(xb + m0g * K_DIM + 64,         32768);
  STG(xb + (m0g + 128) * K_DIM + 64, 32768 + 16384);
  asm volatile("s_waitcnt vmcnt(4)");
  __builtin_amdgcn_sched_barrier(0);
  __builtin_amdgcn_s_barrier();

  bf16x8 af_a[2][2], af_b[2][2], bq[4][2];
  f32x4 acc[8][4] = {};

  int sAr = 0, sAn = 32768, sAs = 65536;   // A slots: read(t), read(t+1), stage(t+2)

  if ((wid & 1) == 0) {
    RD_A2(af_a, 0, sAr);     // preload first m-pair for t=0
    for (int t = 0; t < KSTEPS; ++t) {
      TILE_SETUP
      TILE_BODY(0)
      TILE_BOUND
    }
  } else {
    RD_A2(af_a, 4, sAr);     // odd waves start their ring at m45
    for (int t = 0; t < KSTEPS; ++t) {
      TILE_SETUP
      TILE_BODY(4)
      TILE_BOUND
    }
  }

  // ---- epilogue: C/D layout col=lane&15, row=hi*4+reg; nontemporal ----
  const long crow = m0g + wr * 128 + hi * 4;
  const long ccol = n0g + wc * 64 + r16;
#pragma unroll
  for (int m = 0; m < 8; ++m)
#pragma unroll
    for (int n = 0; n < 4; ++n)
#pragma unroll
      for (int r = 0; r < 4; ++r)
        __builtin_nontemporal_store(
            acc[m][n][r], &C[(crow + m * 16 + r) * N_DIM + ccol + n * 16]);
}

// ---------------- fallback (no workspace): fused 128^2 kernel ----------------
__global__ __launch_bounds__(256) void gemm_fallback(
    const float* __restrict__ Xf, const int* __restrict__ qw,
    const int* __restrict__ qs, const float* __restrict__ qf,
    const float* __restrict__ meanp, float* __restrict__ C) {
  __shared__ unsigned short As[128 * 64];
  __shared__ unsigned short Bs[128 * 64];
  __shared__ float tbl[16];
  const int tid = threadIdx.x;
  if (tid < 16) tbl[tid] = NF4_TBL[tid];
  const float mu = meanp[0];
  const int nwg = (M_ROWS / 128) * (N_DIM / 128);
  const int wg = ((int)blockIdx.x & 7) * (nwg / 8) + ((int)blockIdx.x >> 3);
  const int mbf = wg % (M_ROWS / 128), nbf = wg / (M_ROWS / 128);
  const int m0 = mbf * 128, n0 = nbf * 128;
  const int wid = tid >> 6, lane = tid & 63;
  const int wrf = wid >> 1, wcc = wid & 1;
  const int r16 = lane & 15, hi = lane >> 4;
  f32x4 acc[4][4] = {};
  for (int t = 0; t < KSTEPS; ++t) {
    const int k0 = t * 64;
    __syncthreads();
#pragma unroll
    for (int i = 0; i < 4; ++i) {
      int gi = i * 256 + tid;
      int row = gi >> 3, kq = (gi & 7) * 8;
      const float* px = Xf + (long)(m0 + row) * K_DIM + k0 + kq;
      f32x4 v0 = *(const f32x4*)px;
      f32x4 v1 = *(const f32x4*)(px + 4);
      u16x8 o;
      o[0] = f2bf(v0[0]); o[1] = f2bf(v0[1]); o[2] = f2bf(v0[2]); o[3] = f2bf(v0[3]);
      o[4] = f2bf(v1[0]); o[5] = f2bf(v1[1]); o[6] = f2bf(v1[2]); o[7] = f2bf(v1[3]);
      *(u16x8*)&As[row * 64 + kq] = o;
    }
#pragma unroll
    for (int i = 0; i < 4; ++i) {
      int gi = i * 256 + tid;
      int row = gi >> 3, kq = (gi & 7) * 8;
      const int* pq = qw + (long)(n0 + row) * K_DIM + k0 + kq;
      i32x4 q0 = *(const i32x4*)pq;
      i32x4 q1 = *(const i32x4*)(pq + 4);
      int g = (n0 + row) * (K_DIM / 64) + t;
      float s = (float)qs[g] / qf[g >> 8] + mu;
      u16x8 o;
      o[0] = f2bf(tbl[q0[0]] * s); o[1] = f2bf(tbl[q0[1]] * s);
      o[2] = f2bf(tbl[q0[2]] * s); o[3] = f2bf(tbl[q0[3]] * s);
      o[4] = f2bf(tbl[q1[0]] * s); o[5] = f2bf(tbl[q1[1]] * s);
      o[6] = f2bf(tbl[q1[2]] * s); o[7] = f2bf(tbl[q1[3]] * s);
      *(u16x8*)&Bs[row * 64 + kq] = o;
    }
    __syncthreads();
    bf16x8 afr[4][2], bfr[4][2];
#pragma unroll
    for (int i = 0; i < 4; ++i)
#pragma unroll
      for (int h = 0; h < 2; ++h) {
        afr[i][h] = *(const bf16x8*)&As[(wrf * 64 + i * 16 + r16) * 64 + h * 32 + hi * 8];
        bfr[i][h] = *(const bf16x8*)&Bs[(wcc * 64 + i * 16 + r16) * 64 + h * 32 + hi * 8];
      }
#pragma unroll
    for (int i = 0; i < 4; ++i)
#pragma unroll
      for (int j = 0; j < 4; ++j) {
        acc[i][j] = __builtin_amdgcn_mfma_f32_16x16x32_bf16(afr[i][0], bfr[j][0], acc[i][j], 0, 0, 0);
        acc[i][j] = __builtin_amdgcn_mfma_f32_16x16x32_bf16(afr[i][1], bfr[j][1], acc[i][j], 0, 0, 0);
      }
  }
  const int crow = m0 + wrf * 64 + hi * 4;
  const int ccol = n0 + wcc * 64 + r16;
#pragma unroll
  for (int i = 0; i < 4; ++i)
#pragma unroll
    for (int j = 0; j < 4; ++j)
#pragma unroll
      for (int r = 0; r < 4; ++r)
        C[(long)(crow + i * 16 + r) * N_DIM + (ccol + j * 16)] = acc[i][j][r];
}

extern "C" void kernel_launch(void* const* d_in, const int* in_sizes, int n_in,
                              void* d_out, int out_size, void* d_ws, size_t ws_size,
                              hipStream_t stream) {
  const float* x    = (const float*)d_in[0];
  const int*   qw   = (const int*)d_in[1];
  const int*   qs   = (const int*)d_in[2];
  const float* qf   = (const float*)d_in[3];
  const float* mean = (const float*)d_in[4];
  float* out = (float*)d_out;

  const size_t xb_bytes = (size_t)M_ROWS * K_DIM * 2;  // 64 MiB
  const size_t wb_bytes = (size_t)N_DIM * K_DIM * 2;   // 86 MiB

  if (ws_size >= xb_bytes + wb_bytes) {
    unsigned short* xb = (unsigned short*)d_ws;
    unsigned short* wb = (unsigned short*)((char*)d_ws + xb_bytes);
    convert_x_kernel<<<4096, 256, 0, stream>>>(x, xb);
    dequant_w_kernel<<<4096, 256, 0, stream>>>(qw, qs, qf, mean, wb);
    gemm_pipe<<<NWG, 512, 0, stream>>>(xb, wb, out);
  } else {
    gemm_fallback<<<(M_ROWS / 128) * (N_DIM / 128), 256, 0, stream>>>(
        x, qw, qs, qf, mean, out);
  }
}

// Round 14
// 685.175 us; speedup vs baseline: 1.1229x; 1.0040x over previous
//
#include <hip/hip_runtime.h>
#include <stdint.h>

#define M_ROWS 8192
#define K_DIM  4096
#define N_DIM  11008
#define KSTEPS (K_DIM / 64)      // 64 K-tiles of BK=64

// ---- 256x256 geometry, 8 waves (2M x 4N), per-wave output 128x64 ----
#define BM 256
#define BN 256
#define MBLKS (M_ROWS / BM)      // 32
#define NBLKS (N_DIM / BN)       // 43
#define NWG   (MBLKS * NBLKS)    // 1376
#define NWG_SPLIT 1472           // 1280 full-K + 192 half-K (96 tail tiles x 2)

typedef __attribute__((ext_vector_type(4))) float          f32x4;
typedef __attribute__((ext_vector_type(8))) __bf16         bf16x8;
typedef __attribute__((ext_vector_type(4))) int            i32x4;
typedef __attribute__((ext_vector_type(8))) unsigned short u16x8;

__constant__ float NF4_TBL[16] = {
    -1.0f, -0.6961928009986877f, -0.5250730514526367f, -0.39491748809814453f,
    -0.28444138169288635f, -0.18477343022823334f, -0.10644006729125977f,
    -0.029167551919817924f, 0.0f, 0.07958029955625534f, 0.16093020141124725f,
    0.24611230194568634f, 0.33791524171829224f, 0.44070982933044434f,
    0.5626170039176941f, 0.7229568362236023f};

__device__ __forceinline__ unsigned short f2bf(float f) {
  uint32_t u = __float_as_uint(f);
  u += 0x7fffu + ((u >> 16) & 1u);   // RNE
  return (unsigned short)(u >> 16);
}

__device__ __forceinline__ void gload_lds16(const void* g, const void* l) {
  __builtin_amdgcn_global_load_lds(
      (const __attribute__((address_space(1))) void*)(uintptr_t)g,
      (__attribute__((address_space(3))) void*)(uint32_t)(uintptr_t)l,
      16, 0, 0);
}

// ---------------- prep 1: x fp32 -> bf16 ----------------
__global__ void convert_x_kernel(const float* __restrict__ x,
                                 unsigned short* __restrict__ xb) {
  const long n8 = (long)M_ROWS * K_DIM / 8;
  for (long t = (long)blockIdx.x * blockDim.x + threadIdx.x; t < n8;
       t += (long)gridDim.x * blockDim.x) {
    const float* p = x + t * 8;
    f32x4 v0 = *(const f32x4*)p;
    f32x4 v1 = *(const f32x4*)(p + 4);
    u16x8 o;
    o[0] = f2bf(v0[0]); o[1] = f2bf(v0[1]); o[2] = f2bf(v0[2]); o[3] = f2bf(v0[3]);
    o[4] = f2bf(v1[0]); o[5] = f2bf(v1[1]); o[6] = f2bf(v1[2]); o[7] = f2bf(v1[3]);
    *(u16x8*)(xb + t * 8) = o;
  }
}

// ---------------- prep 2: NF4 dequant W -> bf16 ----------------
__global__ void dequant_w_kernel(const int* __restrict__ qw,
                                 const int* __restrict__ qs,
                                 const float* __restrict__ qf,
                                 const float* __restrict__ mean,
                                 unsigned short* __restrict__ wb) {
  __shared__ float tbl[16];
  if (threadIdx.x < 16) tbl[threadIdx.x] = NF4_TBL[threadIdx.x];
  __syncthreads();
  const float mu = mean[0];
  const long n8 = (long)N_DIM * K_DIM / 8;
  for (long t = (long)blockIdx.x * blockDim.x + threadIdx.x; t < n8;
       t += (long)gridDim.x * blockDim.x) {
    long f = t * 8;
    int  g = (int)(f >> 6);
    float s = (float)qs[g] / qf[g >> 8] + mu;
    i32x4 q0 = *(const i32x4*)(qw + f);
    i32x4 q1 = *(const i32x4*)(qw + f + 4);
    u16x8 o;
    o[0] = f2bf(tbl[q0[0]] * s); o[1] = f2bf(tbl[q0[1]] * s);
    o[2] = f2bf(tbl[q0[2]] * s); o[3] = f2bf(tbl[q0[3]] * s);
    o[4] = f2bf(tbl[q1[0]] * s); o[5] = f2bf(tbl[q1[1]] * s);
    o[6] = f2bf(tbl[q1[2]] * s); o[7] = f2bf(tbl[q1[3]] * s);
    *(u16x8*)(wb + f) = o;
  }
}

// ---------------- 256x256 one-barrier-per-tile bf16 GEMM:  C = A * B^T ----------------
// R13 structure EXACTLY (16x16x32 MFMA; A triple buffer slot rotation at
// 0/32768/65536, B double buffer at 98304+par*32768; 8 clusters w/ per-cluster
// SB+setprio; 4 STG/tile; ONE vmcnt(4)+barrier boundary; T2 swizzle; supertile
// map; anti-phase ring +4 for odd waves; cross-tile A pre-read in c6).
// NEW: optional split-K tail. SPLIT grid = 1280 full-K tiles (nb 0..39) + 192
// half-K WGs covering the 96 tail tiles (nb 40..42): khalf=0 computes K-tiles
// [0,32) and writes C; khalf=1 computes [32,64) and writes a per-tile partial
// buffer P (25MB in d_ws). fixup_kernel then does C += P. Flattens the ragged
// 6th dispatch round (10.4% -> ~2% makespan loss). Both halves start at even
// t so LDS parity/slot logic is unchanged; prologue stages at k0=tstart*64;
// kB/kA clamp to tend.
#define STG(GP, LB)                                                              \
  gload_lds16((GP) + (long)srow * K_DIM + scol, &LDSbuf[(LB) + wid * 1024]);     \
  gload_lds16((GP) + (long)(64 + srow) * K_DIM + scol,                           \
              &LDSbuf[(LB) + 8192 + wid * 1024]);

#define SB __builtin_amdgcn_sched_barrier(0)

#define RD_A2(DST, MB, SA)                                                        \
  DST[0][0] = *(const bf16x8*)&LDSbuf[(SA) + aoff + (MB) * 2048 + kswz0];         \
  DST[0][1] = *(const bf16x8*)&LDSbuf[(SA) + aoff + (MB) * 2048 + kswz1];         \
  DST[1][0] = *(const bf16x8*)&LDSbuf[(SA) + aoff + ((MB) + 1) * 2048 + kswz0];   \
  DST[1][1] = *(const bf16x8*)&LDSbuf[(SA) + aoff + ((MB) + 1) * 2048 + kswz1];

#define RD_B2(NB, CB)                                                             \
  bq[NB][0]     = *(const bf16x8*)&LDSbuf[(CB) + boff + (NB) * 2048 + kswz0];     \
  bq[NB][1]     = *(const bf16x8*)&LDSbuf[(CB) + boff + (NB) * 2048 + kswz1];     \
  bq[NB + 1][0] = *(const bf16x8*)&LDSbuf[(CB) + boff + ((NB) + 1) * 2048 + kswz0];\
  bq[NB + 1][1] = *(const bf16x8*)&LDSbuf[(CB) + boff + ((NB) + 1) * 2048 + kswz1];

#define MFP(MI, AF, AI, NI)                                                       \
  acc[MI][NI] = __builtin_amdgcn_mfma_f32_16x16x32_bf16(AF[AI][0], bq[NI][0], acc[MI][NI], 0, 0, 0); \
  acc[MI][NI] = __builtin_amdgcn_mfma_f32_16x16x32_bf16(AF[AI][1], bq[NI][1], acc[MI][NI], 0, 0, 0);

#define TILE_BODY(BASE)                                                           \
    RD_B2(0, cB);                                                                 \
    SB;                                                                           \
    RD_B2(2, cB);                                                                 \
    STG(wb + n0g * K_DIM + kB, nB);                                               \
    __builtin_amdgcn_s_setprio(1);                                                \
    MFP(((BASE) + 0) & 7, af_a, 0, 0) MFP(((BASE) + 1) & 7, af_a, 1, 0)           \
    MFP(((BASE) + 0) & 7, af_a, 0, 1) MFP(((BASE) + 1) & 7, af_a, 1, 1)           \
    __builtin_amdgcn_s_setprio(0);                                                \
    SB;                                                                           \
    RD_A2(af_b, ((BASE) + 2) & 7, sAr);                                           \
    STG(wb + (n0g + 128) * K_DIM + kB, nB + 16384);                               \
    __builtin_amdgcn_s_setprio(1);                                                \
    MFP(((BASE) + 0) & 7, af_a, 0, 2) MFP(((BASE) + 1) & 7, af_a, 1, 2)           \
    MFP(((BASE) + 0) & 7, af_a, 0, 3) MFP(((BASE) + 1) & 7, af_a, 1, 3)           \
    __builtin_amdgcn_s_setprio(0);                                                \
    SB;                                                                           \
    STG(xb + m0g * K_DIM + kA, sAs);                                              \
    __builtin_amdgcn_s_setprio(1);                                                \
    MFP(((BASE) + 2) & 7, af_b, 0, 2) MFP(((BASE) + 3) & 7, af_b, 1, 2)           \
    MFP(((BASE) + 2) & 7, af_b, 0, 3) MFP(((BASE) + 3) & 7, af_b, 1, 3)           \
    __builtin_amdgcn_s_setprio(0);                                                \
    SB;                                                                           \
    RD_A2(af_a, ((BASE) + 4) & 7, sAr);                                           \
    STG(xb + (m0g + 128) * K_DIM + kA, sAs + 16384);                              \
    __builtin_amdgcn_s_setprio(1);                                                \
    MFP(((BASE) + 2) & 7, af_b, 0, 0) MFP(((BASE) + 3) & 7, af_b, 1, 0)           \
    MFP(((BASE) + 2) & 7, af_b, 0, 1) MFP(((BASE) + 3) & 7, af_b, 1, 1)           \
    __builtin_amdgcn_s_setprio(0);                                                \
    SB;                                                                           \
    __builtin_amdgcn_s_setprio(1);                                                \
    MFP(((BASE) + 4) & 7, af_a, 0, 0) MFP(((BASE) + 5) & 7, af_a, 1, 0)           \
    MFP(((BASE) + 4) & 7, af_a, 0, 1) MFP(((BASE) + 5) & 7, af_a, 1, 1)           \
    __builtin_amdgcn_s_setprio(0);                                                \
    SB;                                                                           \
    RD_A2(af_b, ((BASE) + 6) & 7, sAr);                                           \
    __builtin_amdgcn_s_setprio(1);                                                \
    MFP(((BASE) + 4) & 7, af_a, 0, 2) MFP(((BASE) + 5) & 7, af_a, 1, 2)           \
    MFP(((BASE) + 4) & 7, af_a, 0, 3) MFP(((BASE) + 5) & 7, af_a, 1, 3)           \
    __builtin_amdgcn_s_setprio(0);                                                \
    SB;                                                                           \
    RD_A2(af_a, ((BASE) + 0) & 7, sAn);   /* cross-tile pre-read for t+1 */       \
    __builtin_amdgcn_s_setprio(1);                                                \
    MFP(((BASE) + 6) & 7, af_b, 0, 2) MFP(((BASE) + 7) & 7, af_b, 1, 2)           \
    MFP(((BASE) + 6) & 7, af_b, 0, 3) MFP(((BASE) + 7) & 7, af_b, 1, 3)           \
    __builtin_amdgcn_s_setprio(0);                                                \
    SB;                                                                           \
    __builtin_amdgcn_s_setprio(1);                                                \
    MFP(((BASE) + 6) & 7, af_b, 0, 0) MFP(((BASE) + 7) & 7, af_b, 1, 0)           \
    MFP(((BASE) + 6) & 7, af_b, 0, 1) MFP(((BASE) + 7) & 7, af_b, 1, 1)           \
    __builtin_amdgcn_s_setprio(0);

#define TILE_SETUP                                                                \
    const int cur = t & 1;                                                        \
    const int cB = 98304 + cur * 32768;                                           \
    const int nB = 98304 + (cur ^ 1) * 32768;                                     \
    const long kB = (long)((t + 1 < tend ? t + 1 : tend - 1) * 64);               \
    const long kA = (long)((t + 2 < tend ? t + 2 : tend - 1) * 64);

#define TILE_BOUND                                                                \
    asm volatile("s_waitcnt vmcnt(4)");                                           \
    __builtin_amdgcn_sched_barrier(0);                                            \
    __builtin_amdgcn_s_barrier();                                                 \
    __builtin_amdgcn_sched_barrier(0);                                            \
    int tmp = sAr; sAr = sAn; sAn = sAs; sAs = tmp;

template <bool SPLIT>
__global__ __launch_bounds__(512, 2) void gemm_pipe(
    const unsigned short* __restrict__ xb, const unsigned short* __restrict__ wb,
    float* __restrict__ C, float* __restrict__ P) {
  __align__(16) __shared__ unsigned char LDSbuf[163840];   // 96K A(3) + 64K B(2)

  const int tid = threadIdx.x;
  const int wid = tid >> 6, lane = tid & 63;
  const int wr = wid >> 2, wc = wid & 3;
  const int r16 = lane & 15, hi = lane >> 4;

  // ---- tile mapping ----
  int mb, nb, tstart = 0, tend = KSTEPS;
  bool partial = false;
  long ptile = 0;
  if (!SPLIT) {
    const int p = ((int)blockIdx.x & 7) * (NWG / 8) + ((int)blockIdx.x >> 3);
    if (p < 1280) {
      const int nbg = p >> 7, rem = p & 127, mbg = rem >> 5, s = rem & 31;
      mb = mbg * 8 + (s & 7);
      nb = nbg * 4 + (s >> 3);
    } else {
      const int q = p - 1280, mbg = q / 24, s = q % 24;
      mb = mbg * 8 + (s & 7);
      nb = 40 + (s >> 3);
    }
  } else {
    const int bx = (int)blockIdx.x;
    if (bx < 1280) {              // full-K tiles, nb 0..39
      const int p = (bx & 7) * 160 + (bx >> 3);
      const int nbg = p >> 7, rem = p & 127, mbg = rem >> 5, s = rem & 31;
      mb = mbg * 8 + (s & 7);
      nb = nbg * 4 + (s >> 3);
    } else {                      // 192 half-K WGs over 96 tail tiles (nb 40..42)
      const int q = bx - 1280, r = q >> 1, kh = q & 1;
      const int mbg = r / 24, s = r % 24;
      mb = mbg * 8 + (s & 7);
      nb = 40 + (s >> 3);
      tstart = kh << 5;           // 0 or 32 (even -> parity logic unchanged)
      tend   = tstart + 32;
      partial = (kh == 1);
      ptile = (long)r << 16;      // r * 256*256
    }
  }
  const long m0g = (long)mb * BM, n0g = (long)nb * BN;

  // staging coords (per lane); T2: linear LDS dest, inverse-swizzled source
  const int srow = wid * 8 + (lane >> 3);
  const int scol = ((lane & 7) ^ (lane >> 3)) * 8;

  // ds_read coords (T2 swizzle on read)
  const int aoff = (wr * 128 + r16) * 128;
  const int boff = (wc * 64 + r16) * 128;
  const int kswz0 = ((hi ^ (r16 & 7)) << 4);
  const int kswz1 = kswz0 ^ 64;

  // ---- prologue: A(ts)->slot0, B(ts)->par0, A(ts+1)->slot1; wait all but A(ts+1) ----
  const long k0p = (long)tstart * 64;
  STG(xb + m0g * K_DIM + k0p,              0);
  STG(xb + (m0g + 128) * K_DIM + k0p,      16384);
  STG(wb + n0g * K_DIM + k0p,              98304);
  STG(wb + (n0g + 128) * K_DIM + k0p,      98304 + 16384);
  STG(xb + m0g * K_DIM + k0p + 64,         32768);
  STG(xb + (m0g + 128) * K_DIM + k0p + 64, 32768 + 16384);
  asm volatile("s_waitcnt vmcnt(4)");
  __builtin_amdgcn_sched_barrier(0);
  __builtin_amdgcn_s_barrier();

  bf16x8 af_a[2][2], af_b[2][2], bq[4][2];
  f32x4 acc[8][4] = {};

  int sAr = 0, sAn = 32768, sAs = 65536;   // A slots: read(t), read(t+1), stage(t+2)

  if ((wid & 1) == 0) {
    RD_A2(af_a, 0, sAr);     // preload first m-pair
    for (int t = tstart; t < tend; ++t) {
      TILE_SETUP
      TILE_BODY(0)
      TILE_BOUND
    }
  } else {
    RD_A2(af_a, 4, sAr);     // odd waves start their ring at m45
    for (int t = tstart; t < tend; ++t) {
      TILE_SETUP
      TILE_BODY(4)
      TILE_BOUND
    }
  }

  // ---- epilogue: C/D layout col=lane&15, row=hi*4+reg; nontemporal ----
  if (SPLIT && partial) {
    float* Pt = P + ptile;
    const int prow = wr * 128 + hi * 4;
    const int pcol = wc * 64 + r16;
#pragma unroll
    for (int m = 0; m < 8; ++m)
#pragma unroll
      for (int n = 0; n < 4; ++n)
#pragma unroll
        for (int r = 0; r < 4; ++r)
          __builtin_nontemporal_store(
              acc[m][n][r], &Pt[(prow + m * 16 + r) * 256 + pcol + n * 16]);
  } else {
    const long crow = m0g + wr * 128 + hi * 4;
    const long ccol = n0g + wc * 64 + r16;
#pragma unroll
    for (int m = 0; m < 8; ++m)
#pragma unroll
      for (int n = 0; n < 4; ++n)
#pragma unroll
        for (int r = 0; r < 4; ++r)
          __builtin_nontemporal_store(
              acc[m][n][r], &C[(crow + m * 16 + r) * N_DIM + ccol + n * 16]);
  }
}

// ---------------- fixup: C[tail region] += P (96 tiles x 256x256) ----------------
__global__ void fixup_kernel(float* __restrict__ C, const float* __restrict__ P) {
  const long n4 = 96L * 16384;   // float4 count
  for (long i = (long)blockIdx.x * blockDim.x + threadIdx.x; i < n4;
       i += (long)gridDim.x * blockDim.x) {
    const int r = (int)(i >> 14);
    const int w = (int)(i & 16383);
    const int row = w >> 6, c4 = (w & 63) * 4;
    const int mbg = r / 24, s = r % 24;
    const int mb = mbg * 8 + (s & 7), nb = 40 + (s >> 3);
    float* cp = C + (long)(mb * 256 + row) * N_DIM + nb * 256 + c4;
    const f32x4 pv = *(const f32x4*)(P + i * 4);
    f32x4 cv = *(const f32x4*)cp;
    cv += pv;
    *(f32x4*)cp = cv;
  }
}

// ---------------- fallback (no workspace): fused 128^2 kernel ----------------
__global__ __launch_bounds__(256) void gemm_fallback(
    const float* __restrict__ Xf, const int* __restrict__ qw,
    const int* __restrict__ qs, const float* __restrict__ qf,
    const float* __restrict__ meanp, float* __restrict__ C) {
  __shared__ unsigned short As[128 * 64];
  __shared__ unsigned short Bs[128 * 64];
  __shared__ float tbl[16];
  const int tid = threadIdx.x;
  if (tid < 16) tbl[tid] = NF4_TBL[tid];
  const float mu = meanp[0];
  const int nwg = (M_ROWS / 128) * (N_DIM / 128);
  const int wg = ((int)blockIdx.x & 7) * (nwg / 8) + ((int)blockIdx.x >> 3);
  const int mbf = wg % (M_ROWS / 128), nbf = wg / (M_ROWS / 128);
  const int m0 = mbf * 128, n0 = nbf * 128;
  const int wid = tid >> 6, lane = tid & 63;
  const int wrf = wid >> 1, wcc = wid & 1;
  const int r16 = lane & 15, hi = lane >> 4;
  f32x4 acc[4][4] = {};
  for (int t = 0; t < KSTEPS; ++t) {
    const int k0 = t * 64;
    __syncthreads();
#pragma unroll
    for (int i = 0; i < 4; ++i) {
      int gi = i * 256 + tid;
      int row = gi >> 3, kq = (gi & 7) * 8;
      const float* px = Xf + (long)(m0 + row) * K_DIM + k0 + kq;
      f32x4 v0 = *(const f32x4*)px;
      f32x4 v1 = *(const f32x4*)(px + 4);
      u16x8 o;
      o[0] = f2bf(v0[0]); o[1] = f2bf(v0[1]); o[2] = f2bf(v0[2]); o[3] = f2bf(v0[3]);
      o[4] = f2bf(v1[0]); o[5] = f2bf(v1[1]); o[6] = f2bf(v1[2]); o[7] = f2bf(v1[3]);
      *(u16x8*)&As[row * 64 + kq] = o;
    }
#pragma unroll
    for (int i = 0; i < 4; ++i) {
      int gi = i * 256 + tid;
      int row = gi >> 3, kq = (gi & 7) * 8;
      const int* pq = qw + (long)(n0 + row) * K_DIM + k0 + kq;
      i32x4 q0 = *(const i32x4*)pq;
      i32x4 q1 = *(const i32x4*)(pq + 4);
      int g = (n0 + row) * (K_DIM / 64) + t;
      float s = (float)qs[g] / qf[g >> 8] + mu;
      u16x8 o;
      o[0] = f2bf(tbl[q0[0]] * s); o[1] = f2bf(tbl[q0[1]] * s);
      o[2] = f2bf(tbl[q0[2]] * s); o[3] = f2bf(tbl[q0[3]] * s);
      o[4] = f2bf(tbl[q1[0]] * s); o[5] = f2bf(tbl[q1[1]] * s);
      o[6] = f2bf(tbl[q1[2]] * s); o[7] = f2bf(tbl[q1[3]] * s);
      *(u16x8*)&Bs[row * 64 + kq] = o;
    }
    __syncthreads();
    bf16x8 afr[4][2], bfr[4][2];
#pragma unroll
    for (int i = 0; i < 4; ++i)
#pragma unroll
      for (int h = 0; h < 2; ++h) {
        afr[i][h] = *(const bf16x8*)&As[(wrf * 64 + i * 16 + r16) * 64 + h * 32 + hi * 8];
        bfr[i][h] = *(const bf16x8*)&Bs[(wcc * 64 + i * 16 + r16) * 64 + h * 32 + hi * 8];
      }
#pragma unroll
    for (int i = 0; i < 4; ++i)
#pragma unroll
      for (int j = 0; j < 4; ++j) {
        acc[i][j] = __builtin_amdgcn_mfma_f32_16x16x32_bf16(afr[i][0], bfr[j][0], acc[i][j], 0, 0, 0);
        acc[i][j] = __builtin_amdgcn_mfma_f32_16x16x32_bf16(afr[i][1], bfr[j][1], acc[i][j], 0, 0, 0);
      }
  }
  const int crow = m0 + wrf * 64 + hi * 4;
  const int ccol = n0 + wcc * 64 + r16;
#pragma unroll
  for (int i = 0; i < 4; ++i)
#pragma unroll
    for (int j = 0; j < 4; ++j)
#pragma unroll
      for (int r = 0; r < 4; ++r)
        C[(long)(crow + i * 16 + r) * N_DIM + (ccol + j * 16)] = acc[i][j][r];
}

extern "C" void kernel_launch(void* const* d_in, const int* in_sizes, int n_in,
                              void* d_out, int out_size, void* d_ws, size_t ws_size,
                              hipStream_t stream) {
  const float* x    = (const float*)d_in[0];
  const int*   qw   = (const int*)d_in[1];
  const int*   qs   = (const int*)d_in[2];
  const float* qf   = (const float*)d_in[3];
  const float* mean = (const float*)d_in[4];
  float* out = (float*)d_out;

  const size_t xb_bytes = (size_t)M_ROWS * K_DIM * 2;   // 64 MiB
  const size_t wb_bytes = (size_t)N_DIM * K_DIM * 2;    // 86 MiB
  const size_t p_bytes  = (size_t)96 * 65536 * 4;       // 24 MiB split-K partials

  if (ws_size >= xb_bytes + wb_bytes + p_bytes) {
    unsigned short* xb = (unsigned short*)d_ws;
    unsigned short* wb = (unsigned short*)((char*)d_ws + xb_bytes);
    float* P = (float*)((char*)d_ws + xb_bytes + wb_bytes);
    convert_x_kernel<<<4096, 256, 0, stream>>>(x, xb);
    dequant_w_kernel<<<4096, 256, 0, stream>>>(qw, qs, qf, mean, wb);
    gemm_pipe<true><<<NWG_SPLIT, 512, 0, stream>>>(xb, wb, out, P);
    fixup_kernel<<<2048, 256, 0, stream>>>(out, P);
  } else if (ws_size >= xb_bytes + wb_bytes) {
    unsigned short* xb = (unsigned short*)d_ws;
    unsigned short* wb = (unsigned short*)((char*)d_ws + xb_bytes);
    convert_x_kernel<<<4096, 256, 0, stream>>>(x, xb);
    dequant_w_kernel<<<4096, 256, 0, stream>>>(qw, qs, qf, mean, wb);
    gemm_pipe<false><<<NWG, 512, 0, stream>>>(xb, wb, out, nullptr);
  } else {
    gemm_fallback<<<(M_ROWS / 128) * (N_DIM / 128), 256, 0, stream>>>(
        x, qw, qs, qf, mean, out);
  }
}